// Round 6
// baseline (26.580 us; speedup 1.0000x reference)
//
#include <hip/hip_runtime.h>
#include <cstdint>
#include <cstddef>

typedef _Float16 half8 __attribute__((ext_vector_type(8)));
typedef float f32x4 __attribute__((ext_vector_type(4)));

static constexpr int kN   = 256;          // state dim (N == K)
static constexpr int kKS  = 8;            // k-steps of 32
static constexpr int kNTb = 8;            // n-tiles per block (BN = 128)
static constexpr int kBM  = 128;          // rows per block (8 waves x 16)
static constexpr size_t kABytes = (size_t)kN * kN * 2;   // 128 KiB packed f16 A
static constexpr size_t kLDS    = kABytes / 2;           // 64 KiB per block (one n-half)

// Pack A_stacked[t] (fp32 row-major [n][k]) into f16 MFMA B-fragment order,
// nt-major: a16[((nt*8 + ks)*64 + l)*8 + j] = A[nt*16 + (l&15)][ks*32 + (l>>4)*8 + j]
// -> n-half nh occupies the contiguous 64 KiB at offset nh*65536.
__global__ __launch_bounds__(256) void hippo_prep(
    const float* __restrict__ A_stacked, const int* __restrict__ tptr,
    _Float16* __restrict__ a16)
{
    const int t = tptr[0];
    const float* __restrict__ A = A_stacked + (size_t)t * kN * kN;
    const int tid = blockIdx.x * 256 + threadIdx.x;   // 0..8191
    const int nt = tid >> 9;
    const int ks = (tid >> 6) & 7;
    const int l  = tid & 63;
    const int row = nt * 16 + (l & 15);
    const int k0  = ks * 32 + ((l >> 4) << 3);
    const float* __restrict__ src = A + row * kN + k0;
    f32x4 v0 = *(const f32x4*)(src);
    f32x4 v1 = *(const f32x4*)(src + 4);
    half8 h;
    h[0] = (_Float16)v0[0]; h[1] = (_Float16)v0[1];
    h[2] = (_Float16)v0[2]; h[3] = (_Float16)v0[3];
    h[4] = (_Float16)v1[0]; h[5] = (_Float16)v1[1];
    h[6] = (_Float16)v1[2]; h[7] = (_Float16)v1[3];
    ((half8*)a16)[tid] = h;
}

// out[m][n] = sum_k c[m][k] * A_t[n][k] + b[n] * f[m]
// Block (mb, nh): rows [mb*128,+128) x cols [nh*128,+128). LDS = 64 KiB
// (one n-half of packed A, DMA-staged) -> 2 blocks/CU, 4 waves/SIMD.
__global__ __launch_bounds__(512, 4) void hippo_gemm(
    const float* __restrict__ c, const float* __restrict__ f,
    const float* __restrict__ Bst, const int* __restrict__ tptr,
    const _Float16* __restrict__ a16, float* __restrict__ out)
{
    extern __shared__ char lds_raw[];

    const int tid  = threadIdx.x;
    const int l    = tid & 63;
    const int wid  = tid >> 6;          // 0..7
    const int lo16 = l & 15;
    const int hi4  = l >> 4;

    const int bid = blockIdx.x;
    const int mb  = bid & 255;          // pair members (nh=0/1) are 256 apart -> same XCD
    const int nh  = bid >> 8;           // 0..1
    const int m0  = mb * kBM + wid * 16;
    const int n0  = nh * 128;

    // ---- 1) c loads first (deepest latency; oldest in VMEM queue) ----
    const float* __restrict__ cptr = c + (size_t)(m0 + lo16) * kN + (hi4 << 3);
    f32x4 cv0[kKS], cv1[kKS];
    #pragma unroll
    for (int ks = 0; ks < kKS; ++ks) {
        cv0[ks] = *(const f32x4*)(cptr + ks * 32);
        cv1[ks] = *(const f32x4*)(cptr + ks * 32 + 4);
    }

    // ---- 2) bias loads ----
    const int t = tptr[0];
    const float* __restrict__ brow = Bst + (size_t)t * kN + n0;
    float bvs[kNTb];
    #pragma unroll
    for (int nt = 0; nt < kNTb; ++nt) bvs[nt] = brow[nt * 16 + lo16];
    float fv[4];
    #pragma unroll
    for (int r = 0; r < 4; ++r) fv[r] = f[m0 + (hi4 << 2) + r];

    // ---- 3) DMA-stage this block's 64 KiB n-half of packed A into LDS ----
    {
        const char* __restrict__ gsrc = (const char*)a16 + (size_t)nh * kLDS;
        #pragma unroll
        for (int i = 0; i < 8; ++i) {
            const int chunk = i * 8 + wid;                 // 0..63, 1 KiB each
            const size_t off = (size_t)chunk * 1024 + (size_t)l * 16;
            __builtin_amdgcn_global_load_lds(
                (const __attribute__((address_space(1))) void*)(gsrc + off),
                (__attribute__((address_space(3))) void*)(lds_raw + off),
                16, 0, 0);
        }
    }

    // ---- 4) cvt c -> f16 A-frags (waits c only; staging still in flight) ----
    half8 af[kKS];
    #pragma unroll
    for (int ks = 0; ks < kKS; ++ks) {
        af[ks][0] = (_Float16)cv0[ks][0]; af[ks][1] = (_Float16)cv0[ks][1];
        af[ks][2] = (_Float16)cv0[ks][2]; af[ks][3] = (_Float16)cv0[ks][3];
        af[ks][4] = (_Float16)cv1[ks][0]; af[ks][5] = (_Float16)cv1[ks][1];
        af[ks][6] = (_Float16)cv1[ks][2]; af[ks][7] = (_Float16)cv1[ks][3];
    }

    __syncthreads();   // staging complete

    // ---- 5) MFMA: ks-outer, nt inner (8 independent acc chains) ----
    f32x4 acc[kNTb];
    #pragma unroll
    for (int i = 0; i < kNTb; ++i) acc[i] = (f32x4){0.f, 0.f, 0.f, 0.f};

    const half8* __restrict__ Bs = (const half8*)lds_raw;
    #pragma unroll
    for (int ks = 0; ks < kKS; ++ks) {
        #pragma unroll
        for (int nt = 0; nt < kNTb; ++nt) {
            half8 bf = Bs[(nt * kKS + ks) * 64 + l];
            acc[nt] = __builtin_amdgcn_mfma_f32_16x16x32_f16(af[ks], bf, acc[nt], 0, 0, 0);
        }
    }

    // ---- 6) epilogue ----
    float* __restrict__ obase = out + (size_t)(m0 + (hi4 << 2)) * kN + n0 + lo16;
    #pragma unroll
    for (int nt = 0; nt < kNTb; ++nt) {
        #pragma unroll
        for (int r = 0; r < 4; ++r)
            obase[(size_t)r * kN + nt * 16] = acc[nt][r] + bvs[nt] * fv[r];
    }
}

extern "C" void kernel_launch(void* const* d_in, const int* in_sizes, int n_in,
                              void* d_out, int out_size, void* d_ws, size_t ws_size,
                              hipStream_t stream) {
    const float* c   = (const float*)d_in[0];
    const float* f   = (const float*)d_in[1];
    const float* A   = (const float*)d_in[2];
    const float* B   = (const float*)d_in[3];
    const int*   t   = (const int*)d_in[4];
    float* out = (float*)d_out;
    _Float16* a16 = (_Float16*)d_ws;   // 128 KiB packed A[t] f16, nt-major

    const int batch = in_sizes[0] / kN;   // 32768

    hipFuncSetAttribute((const void*)hippo_gemm,
                        hipFuncAttributeMaxDynamicSharedMemorySize,
                        (int)kLDS);

    hipLaunchKernelGGL(hippo_prep, dim3(32), dim3(256), 0, stream, A, t, a16);
    // grid: mb major (0..255), nh minor-by-256 so c-sharing pairs land on one XCD
    hipLaunchKernelGGL(hippo_gemm, dim3((batch / kBM) * 2), dim3(512), kLDS, stream,
                       c, f, B, t, a16, out);
}

// Round 7
// 23.461 us; speedup vs baseline: 1.1330x; 1.1330x over previous
//
#include <hip/hip_runtime.h>
#include <cstdint>
#include <cstddef>

typedef _Float16 half8 __attribute__((ext_vector_type(8)));
typedef float f32x4 __attribute__((ext_vector_type(4)));

static constexpr int kN  = 256;          // state dim (N == K)
static constexpr int kKS = 8;            // k-steps of 32
static constexpr int kNT = 16;           // n-tiles of 16
static constexpr int kBM = 128;          // rows per block (8 waves x 16)
static constexpr size_t kABytes = (size_t)kN * kN * 2;  // 128 KiB packed f16 A

// Pack A_stacked[t] (fp32 row-major [n][k]) into f16 MFMA B-fragment order:
// a16[((nt*8 + ks)*64 + l)*8 + j] = A[nt*16 + (l&15)][ks*32 + (l>>4)*8 + j]
__global__ __launch_bounds__(256) void hippo_prep(
    const float* __restrict__ A_stacked, const int* __restrict__ tptr,
    _Float16* __restrict__ a16)
{
    const int t = tptr[0];
    const float* __restrict__ A = A_stacked + (size_t)t * kN * kN;
    const int tid = blockIdx.x * 256 + threadIdx.x;   // 0..8191
    const int nt = tid >> 9;
    const int ks = (tid >> 6) & 7;
    const int l  = tid & 63;
    const int row = nt * 16 + (l & 15);
    const int k0  = ks * 32 + ((l >> 4) << 3);
    const float* __restrict__ src = A + row * kN + k0;
    f32x4 v0 = *(const f32x4*)(src);
    f32x4 v1 = *(const f32x4*)(src + 4);
    half8 h;
    h[0] = (_Float16)v0[0]; h[1] = (_Float16)v0[1];
    h[2] = (_Float16)v0[2]; h[3] = (_Float16)v0[3];
    h[4] = (_Float16)v1[0]; h[5] = (_Float16)v1[1];
    h[6] = (_Float16)v1[2]; h[7] = (_Float16)v1[3];
    ((half8*)a16)[tid] = h;
}

// out[m][n] = sum_k c[m][k] * A_t[n][k] + b[n] * f[m]
// Structure: DMA A->LDS, barrier (cheap drain: only L2 DMA outstanding),
// THEN per-wave c-loads + ks-outer MFMA (fine-grain vmcnt overlap) +
// phase-2 streamed stores. All HBM traffic happens post-barrier, overlapped.
__global__ __launch_bounds__(512, 2) void hippo_gemm(
    const float* __restrict__ c, const float* __restrict__ f,
    const float* __restrict__ Bst, const int* __restrict__ tptr,
    const _Float16* __restrict__ a16, float* __restrict__ out)
{
    extern __shared__ char lds_raw[];

    const int tid  = threadIdx.x;
    const int l    = tid & 63;
    const int wid  = tid >> 6;          // 0..7
    const int lo16 = l & 15;
    const int hi4  = l >> 4;
    const int m0   = blockIdx.x * kBM + wid * 16;

    // ---- DMA-stage packed A (128 KiB) into LDS; nothing else outstanding ----
    #pragma unroll
    for (int i = 0; i < 16; ++i) {
        const int chunk = i * 8 + wid;                 // 0..127, 1 KiB each
        const size_t off = (size_t)chunk * 1024 + (size_t)l * 16;
        __builtin_amdgcn_global_load_lds(
            (const __attribute__((address_space(1))) void*)((const char*)a16 + off),
            (__attribute__((address_space(3))) void*)(lds_raw + off),
            16, 0, 0);
    }
    __syncthreads();   // drains only the A-DMA (L2-fed, ~1 us)

    // ---- post-barrier: per-wave independent work ----
    const int t = tptr[0];
    const float* __restrict__ brow = Bst + (size_t)t * kN;
    float bvs[kNT];
    #pragma unroll
    for (int nt = 0; nt < kNT; ++nt) bvs[nt] = brow[nt * 16 + lo16];
    float fv[4];
    #pragma unroll
    for (int r = 0; r < 4; ++r) fv[r] = f[m0 + (hi4 << 2) + r];

    // c loads (HBM): consumed per-ks; compiler's vmcnt(N) lets MFMA start early
    const float* __restrict__ cptr = c + (size_t)(m0 + lo16) * kN + (hi4 << 3);
    f32x4 cv0[kKS], cv1[kKS];
    #pragma unroll
    for (int ks = 0; ks < kKS; ++ks) {
        cv0[ks] = *(const f32x4*)(cptr + ks * 32);
        cv1[ks] = *(const f32x4*)(cptr + ks * 32 + 4);
    }

    const half8* __restrict__ Bs = (const half8*)lds_raw;
    f32x4 acc[kNT];
    #pragma unroll
    for (int i = 0; i < kNT; ++i) acc[i] = (f32x4){0.f, 0.f, 0.f, 0.f};

    // ---- phase 1: ks 0..3 outer, nt inner (waits only cv[ks] pair) ----
    #pragma unroll
    for (int ks = 0; ks < 4; ++ks) {
        half8 af;
        af[0] = (_Float16)cv0[ks][0]; af[1] = (_Float16)cv0[ks][1];
        af[2] = (_Float16)cv0[ks][2]; af[3] = (_Float16)cv0[ks][3];
        af[4] = (_Float16)cv1[ks][0]; af[5] = (_Float16)cv1[ks][1];
        af[6] = (_Float16)cv1[ks][2]; af[7] = (_Float16)cv1[ks][3];
        #pragma unroll
        for (int nt = 0; nt < kNT; ++nt) {
            half8 bf = Bs[(nt * kKS + ks) * 64 + l];
            acc[nt] = __builtin_amdgcn_mfma_f32_16x16x32_f16(af, bf, acc[nt], 0, 0, 0);
        }
    }

    // ---- phase 2: ks 4..7 per nt-pair + immediate store (writes stream) ----
    half8 af2[4];
    #pragma unroll
    for (int ks = 0; ks < 4; ++ks) {
        af2[ks][0] = (_Float16)cv0[4 + ks][0]; af2[ks][1] = (_Float16)cv0[4 + ks][1];
        af2[ks][2] = (_Float16)cv0[4 + ks][2]; af2[ks][3] = (_Float16)cv0[4 + ks][3];
        af2[ks][4] = (_Float16)cv1[4 + ks][0]; af2[ks][5] = (_Float16)cv1[4 + ks][1];
        af2[ks][6] = (_Float16)cv1[4 + ks][2]; af2[ks][7] = (_Float16)cv1[4 + ks][3];
    }

    float* __restrict__ obase = out + (size_t)(m0 + (hi4 << 2)) * kN + lo16;
    #pragma unroll
    for (int nt = 0; nt < kNT; nt += 2) {
        #pragma unroll
        for (int ks = 0; ks < 4; ++ks) {
            half8 bf0 = Bs[(nt * kKS + 4 + ks) * 64 + l];
            half8 bf1 = Bs[((nt + 1) * kKS + 4 + ks) * 64 + l];
            acc[nt]     = __builtin_amdgcn_mfma_f32_16x16x32_f16(af2[ks], bf0, acc[nt], 0, 0, 0);
            acc[nt + 1] = __builtin_amdgcn_mfma_f32_16x16x32_f16(af2[ks], bf1, acc[nt + 1], 0, 0, 0);
        }
        #pragma unroll
        for (int r = 0; r < 4; ++r) {
            obase[(size_t)r * kN + nt * 16]       = acc[nt][r]     + bvs[nt] * fv[r];
            obase[(size_t)r * kN + (nt + 1) * 16] = acc[nt + 1][r] + bvs[nt + 1] * fv[r];
        }
    }
}

extern "C" void kernel_launch(void* const* d_in, const int* in_sizes, int n_in,
                              void* d_out, int out_size, void* d_ws, size_t ws_size,
                              hipStream_t stream) {
    const float* c   = (const float*)d_in[0];
    const float* f   = (const float*)d_in[1];
    const float* A   = (const float*)d_in[2];
    const float* B   = (const float*)d_in[3];
    const int*   t   = (const int*)d_in[4];
    float* out = (float*)d_out;
    _Float16* a16 = (_Float16*)d_ws;   // 128 KiB packed A[t] f16

    const int batch = in_sizes[0] / kN;   // 32768

    hipFuncSetAttribute((const void*)hippo_gemm,
                        hipFuncAttributeMaxDynamicSharedMemorySize,
                        (int)kABytes);

    hipLaunchKernelGGL(hippo_prep, dim3(32), dim3(256), 0, stream, A, t, a16);
    hipLaunchKernelGGL(hippo_gemm, dim3(batch / kBM), dim3(512), kABytes, stream,
                       c, f, B, t, a16, out);
}